// Round 1
// baseline (681.539 us; speedup 1.0000x reference)
//
#include <hip/hip_runtime.h>
#include <math.h>

#define B_ 512
#define C_ 100
#define E_ 2048
#define F_ 128
#define BK 32
#define PAD 4  // LDS leading-dim pad (floats) to keep float4 alignment & break bank patterns

// ---------------- kernel 1: v_un[c,e] = sum_f W[c,f,e]*u[c,f];  nvsq[c] += sum_e v_un^2
__global__ __launch_bounds__(256)
void k_powiter_v(const float* __restrict__ W, const float* __restrict__ u,
                 float* __restrict__ v_un, float* __restrict__ nvsq) {
    int blk = blockIdx.x;
    int c   = blk >> 3;          // 8 e-chunks of 256 per class
    int ech = blk & 7;
    int e   = ech * 256 + threadIdx.x;

    __shared__ float us[F_];
    if (threadIdx.x < F_) us[threadIdx.x] = u[c * F_ + threadIdx.x];
    __syncthreads();

    const float* Wc = W + (size_t)c * F_ * E_ + e;
    float acc = 0.f;
#pragma unroll 8
    for (int f = 0; f < F_; ++f) acc = fmaf(Wc[(size_t)f * E_], us[f], acc);
    v_un[c * E_ + e] = acc;

    // block-reduce acc^2 -> atomicAdd
    float s = acc * acc;
    for (int off = 32; off; off >>= 1) s += __shfl_down(s, off, 64);
    __shared__ float wsum[4];
    int lane = threadIdx.x & 63, wv = threadIdx.x >> 6;
    if (lane == 0) wsum[wv] = s;
    __syncthreads();
    if (threadIdx.x == 0) atomicAdd(&nvsq[c], wsum[0] + wsum[1] + wsum[2] + wsum[3]);
}

// ---------------- kernel 2: tsq[c] += sum_f (sum_e W[c,f,e]*v_un[c,e])^2
__global__ __launch_bounds__(256)
void k_powiter_t(const float* __restrict__ W, const float* __restrict__ v_un,
                 float* __restrict__ tsq) {
    int blk = blockIdx.x;
    int c  = blk >> 5;           // 32 f-groups of 4 per class
    int fg = blk & 31;
    int wv = threadIdx.x >> 6, lane = threadIdx.x & 63;
    int f  = fg * 4 + wv;        // one wave per f-row

    const float* Wr = W + ((size_t)c * F_ + f) * E_;
    const float* vr = v_un + c * E_;
    float s = 0.f;
#pragma unroll 8
    for (int e = lane; e < E_; e += 64) s = fmaf(Wr[e], vr[e], s);
    for (int off = 32; off; off >>= 1) s += __shfl_down(s, off, 64);
    if (lane == 0) atomicAdd(&tsq[c], s * s);
}

// ---------------- kernel 3: fused  z = (x @ W_c^T)/sigma + b ; dist2 ; exp
// grid: (8 b-tiles, 100 classes), block 256.
// Tile M=64 (b), N=128 (all f), K-loop BK=32.
// Thread (i = t&7, j = t>>3) owns m in {i, i+8, ..., i+56}, f in {j, j+32, j+64, j+96}.
__global__ __launch_bounds__(256)
void k_main(const float* __restrict__ x, const float* __restrict__ W,
            const float* __restrict__ bias, const float* __restrict__ cent,
            const float* __restrict__ nvsq, const float* __restrict__ tsq,
            float* __restrict__ out) {
    const int c  = blockIdx.y;
    const int b0 = blockIdx.x * 64;
    const int t  = threadIdx.x;
    const int i  = t & 7;
    const int j  = t >> 3;

    __shared__ float Xs[64][BK + PAD];
    __shared__ float Ws[128][BK + PAD];

    float acc[8][4];
#pragma unroll
    for (int r = 0; r < 8; ++r)
#pragma unroll
        for (int s = 0; s < 4; ++s) acc[r][s] = 0.f;

    const float* Wc = W + (size_t)c * F_ * E_;

    // staging index precompute
    const int xr = (t * 8) >> 5, xc = (t * 8) & 31;    // X: 8 floats/thread
    const int wr = (t * 16) >> 5, wc = (t * 16) & 31;  // W: 16 floats/thread

    for (int k0 = 0; k0 < E_; k0 += BK) {
        // --- stage X tile (64 x 32)
        {
            const float4* src = (const float4*)(x + (size_t)(b0 + xr) * E_ + k0 + xc);
            float4 p0 = src[0], p1 = src[1];
            *(float4*)&Xs[xr][xc]     = p0;
            *(float4*)&Xs[xr][xc + 4] = p1;
        }
        // --- stage W tile (128 x 32)
        {
            const float4* src = (const float4*)(Wc + (size_t)wr * E_ + k0 + wc);
            float4 q0 = src[0], q1 = src[1], q2 = src[2], q3 = src[3];
            *(float4*)&Ws[wr][wc]      = q0;
            *(float4*)&Ws[wr][wc + 4]  = q1;
            *(float4*)&Ws[wr][wc + 8]  = q2;
            *(float4*)&Ws[wr][wc + 12] = q3;
        }
        __syncthreads();

#pragma unroll
        for (int k = 0; k < BK; k += 4) {
            float4 av[8], bv[4];
#pragma unroll
            for (int r = 0; r < 8; ++r) av[r] = *(const float4*)&Xs[i + 8 * r][k];
#pragma unroll
            for (int s = 0; s < 4; ++s) bv[s] = *(const float4*)&Ws[j + 32 * s][k];
#pragma unroll
            for (int r = 0; r < 8; ++r)
#pragma unroll
                for (int s = 0; s < 4; ++s) {
                    acc[r][s] = fmaf(av[r].x, bv[s].x, acc[r][s]);
                    acc[r][s] = fmaf(av[r].y, bv[s].y, acc[r][s]);
                    acc[r][s] = fmaf(av[r].z, bv[s].z, acc[r][s]);
                    acc[r][s] = fmaf(av[r].w, bv[s].w, acc[r][s]);
                }
        }
        __syncthreads();
    }

    // sigma = ||W v_un|| / ||v_un||  ->  1/sigma = sqrt(nvsq/tsq)
    const float rsigma = sqrtf(nvsq[c] / tsq[c]);

    // per-thread partial dist2 over its 4 f's, for each of its 8 m's
    float part[8];
#pragma unroll
    for (int r = 0; r < 8; ++r) part[r] = 0.f;
#pragma unroll
    for (int s = 0; s < 4; ++s) {
        const int f  = j + 32 * s;
        const float bf = bias[c * F_ + f];
        const float cf = cent[c * F_ + f];
#pragma unroll
        for (int r = 0; r < 8; ++r) {
            float z = fmaf(acc[r][s], rsigma, bf);
            float d = cf - z;
            part[r] = fmaf(d, d, part[r]);
        }
    }

    // reduce over the 32 j-threads per m. Reuse Xs as red[64][33].
    __syncthreads();
    float* red = &Xs[0][0];
#pragma unroll
    for (int r = 0; r < 8; ++r) red[(i + 8 * r) * 33 + j] = part[r];
    __syncthreads();
    if (t < 64) {
        float d2 = 0.f;
#pragma unroll
        for (int q = 0; q < 32; ++q) d2 += red[t * 33 + q];
        out[(size_t)(b0 + t) * C_ + c] = expf(-0.5f * d2);
    }
}

extern "C" void kernel_launch(void* const* d_in, const int* in_sizes, int n_in,
                              void* d_out, int out_size, void* d_ws, size_t ws_size,
                              hipStream_t stream) {
    const float* x  = (const float*)d_in[0];
    const float* W  = (const float*)d_in[1];
    const float* b  = (const float*)d_in[2];
    const float* u  = (const float*)d_in[3];
    const float* cc = (const float*)d_in[4];
    float* out = (float*)d_out;

    // workspace layout
    float* v_un = (float*)d_ws;                         // C*E floats = 819200 B
    float* nvsq = (float*)((char*)d_ws + (size_t)C_ * E_ * 4);   // C floats
    float* tsq  = nvsq + C_;                            // C floats

    hipMemsetAsync(nvsq, 0, 2 * C_ * sizeof(float), stream);

    k_powiter_v<<<C_ * 8, 256, 0, stream>>>(W, u, v_un, nvsq);
    k_powiter_t<<<C_ * 32, 256, 0, stream>>>(W, v_un, tsq);

    dim3 grid(B_ / 64, C_);
    k_main<<<grid, 256, 0, stream>>>(x, W, b, cc, nvsq, tsq, out);
}

// Round 2
// 311.182 us; speedup vs baseline: 2.1902x; 2.1902x over previous
//
#include <hip/hip_runtime.h>
#include <math.h>

#define B_ 512
#define C_ 100
#define E_ 2048
#define F_ 128

typedef _Float16 f16x8 __attribute__((ext_vector_type(8)));
typedef _Float16 f16x4 __attribute__((ext_vector_type(4)));
typedef float    f32x4 __attribute__((ext_vector_type(4)));

// ---------------- kernel 0: x (fp32) -> xh (fp16)
__global__ __launch_bounds__(256)
void k_conv_x(const float* __restrict__ x, _Float16* __restrict__ xh) {
    const int row = blockIdx.x;          // 512 rows
    const int t   = threadIdx.x;         // 8 elems/thread
    const float* src = x + (size_t)row * E_ + t * 8;
    float4 a = *(const float4*)(src);
    float4 b = *(const float4*)(src + 4);
    f16x8 h;
    h[0] = (_Float16)a.x; h[1] = (_Float16)a.y; h[2] = (_Float16)a.z; h[3] = (_Float16)a.w;
    h[4] = (_Float16)b.x; h[5] = (_Float16)b.y; h[6] = (_Float16)b.z; h[7] = (_Float16)b.w;
    *(f16x8*)(xh + (size_t)row * E_ + t * 8) = h;
}

// ---------------- kernel 1: v_un[c,e] = sum_f W[c,f,e]*u[c,f];  nvsq[c] += sum_e v_un^2
__global__ __launch_bounds__(256)
void k_powiter_v(const float* __restrict__ W, const float* __restrict__ u,
                 float* __restrict__ v_un, float* __restrict__ nvsq) {
    int blk = blockIdx.x;
    int c   = blk >> 3;          // 8 e-chunks of 256 per class
    int ech = blk & 7;
    int e   = ech * 256 + threadIdx.x;

    __shared__ float us[F_];
    if (threadIdx.x < F_) us[threadIdx.x] = u[c * F_ + threadIdx.x];
    __syncthreads();

    const float* Wc = W + (size_t)c * F_ * E_ + e;
    float acc = 0.f;
#pragma unroll 8
    for (int f = 0; f < F_; ++f) acc = fmaf(Wc[(size_t)f * E_], us[f], acc);
    v_un[c * E_ + e] = acc;

    float s = acc * acc;
    for (int off = 32; off; off >>= 1) s += __shfl_down(s, off, 64);
    __shared__ float wsum[4];
    int lane = threadIdx.x & 63, wv = threadIdx.x >> 6;
    if (lane == 0) wsum[wv] = s;
    __syncthreads();
    if (threadIdx.x == 0) atomicAdd(&nvsq[c], wsum[0] + wsum[1] + wsum[2] + wsum[3]);
}

// ---------------- kernel 2: tsq[c] += sum_f (W v_un)_f^2 ; also W -> Wh (fp16)
__global__ __launch_bounds__(256)
void k_powiter_t(const float* __restrict__ W, const float* __restrict__ v_un,
                 float* __restrict__ tsq, _Float16* __restrict__ Wh) {
    int blk = blockIdx.x;
    int c  = blk >> 5;           // 32 f-groups of 4 per class
    int fg = blk & 31;
    int wv = threadIdx.x >> 6, lane = threadIdx.x & 63;
    int f  = fg * 4 + wv;        // one wave per f-row

    const float* Wr  = W    + ((size_t)c * F_ + f) * E_;
    const float* vr  = v_un + (size_t)c * E_;
    _Float16*    Whr = Wh   + ((size_t)c * F_ + f) * E_;

    float s = 0.f;
#pragma unroll
    for (int it = 0; it < 8; ++it) {
        int e = it * 256 + lane * 4;
        float4 w4 = *(const float4*)(Wr + e);
        float4 v4 = *(const float4*)(vr + e);
        s = fmaf(w4.x, v4.x, s); s = fmaf(w4.y, v4.y, s);
        s = fmaf(w4.z, v4.z, s); s = fmaf(w4.w, v4.w, s);
        f16x4 h;
        h[0] = (_Float16)w4.x; h[1] = (_Float16)w4.y;
        h[2] = (_Float16)w4.z; h[3] = (_Float16)w4.w;
        *(f16x4*)(Whr + e) = h;
    }
    for (int off = 32; off; off >>= 1) s += __shfl_down(s, off, 64);
    if (lane == 0) atomicAdd(&tsq[c], s * s);
}

// ---------------- kernel 3: fused MFMA GEMM + dist2 + exp
// grid (8 b-tiles, 100 classes), block 256 = 4 waves.
// Tile M=64, N=128 (all f), BK=64. Wave (wm=w&1, wn=w>>1) owns 32x64:
// 2 m-tiles x 4 n-tiles of 16x16, mfma_f32_16x16x32_f16, two 32-k subchunks.
#define BKM 64
#define LDP 72   // 64 + 8 halves pad; 144 B row stride (multiple of 16)

__global__ __launch_bounds__(256)
void k_main(const _Float16* __restrict__ xh, const _Float16* __restrict__ Wh,
            const float* __restrict__ bias, const float* __restrict__ cent,
            const float* __restrict__ nvsq, const float* __restrict__ tsq,
            float* __restrict__ out) {
    const int c  = blockIdx.y;
    const int b0 = blockIdx.x * 64;
    const int t  = threadIdx.x;
    const int w  = t >> 6;
    const int l  = t & 63;
    const int wm = w & 1, wn = w >> 1;
    const int ln = l & 15, quad = l >> 4;

    __shared__ _Float16 XsT[64][LDP];
    __shared__ _Float16 WsT[128][LDP];

    f32x4 acc[2][4];
#pragma unroll
    for (int mt = 0; mt < 2; ++mt)
#pragma unroll
        for (int nt = 0; nt < 4; ++nt) acc[mt][nt] = (f32x4){0.f, 0.f, 0.f, 0.f};

    // staging coords
    const int xrow = t >> 2, xcol = (t & 3) * 16;   // X: 64 rows x 64 halves, 32 B/thread
    const int wrow = t >> 1, wcol = (t & 1) * 32;   // W: 128 rows x 64 halves, 64 B/thread

    const _Float16* Wc = Wh + (size_t)c * F_ * E_;

    for (int k0 = 0; k0 < E_; k0 += BKM) {
        {
            const _Float16* src = xh + (size_t)(b0 + xrow) * E_ + k0 + xcol;
            uint4 a0 = *(const uint4*)(src);
            uint4 a1 = *(const uint4*)(src + 8);
            *(uint4*)&XsT[xrow][xcol]     = a0;
            *(uint4*)&XsT[xrow][xcol + 8] = a1;
        }
        {
            const _Float16* src = Wc + (size_t)wrow * E_ + k0 + wcol;
            uint4 b0v = *(const uint4*)(src);
            uint4 b1v = *(const uint4*)(src + 8);
            uint4 b2v = *(const uint4*)(src + 16);
            uint4 b3v = *(const uint4*)(src + 24);
            *(uint4*)&WsT[wrow][wcol]      = b0v;
            *(uint4*)&WsT[wrow][wcol + 8]  = b1v;
            *(uint4*)&WsT[wrow][wcol + 16] = b2v;
            *(uint4*)&WsT[wrow][wcol + 24] = b3v;
        }
        __syncthreads();

#pragma unroll
        for (int kk = 0; kk < BKM; kk += 32) {
            f16x8 av[2], bv[4];
#pragma unroll
            for (int mt = 0; mt < 2; ++mt)
                av[mt] = *(const f16x8*)&XsT[wm * 32 + mt * 16 + ln][kk + quad * 8];
#pragma unroll
            for (int nt = 0; nt < 4; ++nt)
                bv[nt] = *(const f16x8*)&WsT[wn * 64 + nt * 16 + ln][kk + quad * 8];
#pragma unroll
            for (int mt = 0; mt < 2; ++mt)
#pragma unroll
                for (int nt = 0; nt < 4; ++nt)
                    acc[mt][nt] = __builtin_amdgcn_mfma_f32_16x16x32_f16(
                        av[mt], bv[nt], acc[mt][nt], 0, 0, 0);
        }
        __syncthreads();
    }

    const float rsigma = sqrtf(nvsq[c] / tsq[c]);

    // epilogue: z = acc*rsigma + bias; d2 partial over this lane's 4 f's
    // C/D layout: col (f) = ln, row (m) = quad*4 + reg
    float bi[4], ce[4];
#pragma unroll
    for (int nt = 0; nt < 4; ++nt) {
        int f = wn * 64 + nt * 16 + ln;
        bi[nt] = bias[c * F_ + f];
        ce[nt] = cent[c * F_ + f];
    }

    float* red = (float*)&XsT[0][0];   // red[64][2] floats, reused LDS

#pragma unroll
    for (int mt = 0; mt < 2; ++mt) {
#pragma unroll
        for (int r = 0; r < 4; ++r) {
            float part = 0.f;
#pragma unroll
            for (int nt = 0; nt < 4; ++nt) {
                float z = fmaf(acc[mt][nt][r], rsigma, bi[nt]);
                float d = ce[nt] - z;
                part = fmaf(d, d, part);
            }
            part += __shfl_xor(part, 1, 64);
            part += __shfl_xor(part, 2, 64);
            part += __shfl_xor(part, 4, 64);
            part += __shfl_xor(part, 8, 64);
            if (ln == 0) {
                int m = wm * 32 + mt * 16 + quad * 4 + r;
                red[m * 2 + wn] = part;
            }
        }
    }
    __syncthreads();
    if (t < 64) {
        float d2 = red[t * 2] + red[t * 2 + 1];
        out[(size_t)(b0 + t) * C_ + c] = expf(-0.5f * d2);
    }
}

extern "C" void kernel_launch(void* const* d_in, const int* in_sizes, int n_in,
                              void* d_out, int out_size, void* d_ws, size_t ws_size,
                              hipStream_t stream) {
    const float* x  = (const float*)d_in[0];
    const float* W  = (const float*)d_in[1];
    const float* b  = (const float*)d_in[2];
    const float* u  = (const float*)d_in[3];
    const float* cc = (const float*)d_in[4];
    float* out = (float*)d_out;

    // workspace layout (all 16B aligned)
    char* ws = (char*)d_ws;
    _Float16* Wh   = (_Float16*)ws;                               // C*F*E halves = 52,428,800 B
    _Float16* xh   = (_Float16*)(ws + (size_t)C_ * F_ * E_ * 2);  // B*E halves   =  2,097,152 B
    float*    v_un = (float*)(ws + (size_t)C_ * F_ * E_ * 2 + (size_t)B_ * E_ * 2); // C*E floats
    float*    nvsq = v_un + (size_t)C_ * E_;
    float*    tsq  = nvsq + C_;

    hipMemsetAsync(nvsq, 0, 2 * C_ * sizeof(float), stream);

    k_conv_x<<<B_, 256, 0, stream>>>(x, xh);
    k_powiter_v<<<C_ * 8, 256, 0, stream>>>(W, u, v_un, nvsq);
    k_powiter_t<<<C_ * 32, 256, 0, stream>>>(W, v_un, tsq, Wh);

    dim3 grid(B_ / 64, C_);
    k_main<<<grid, 256, 0, stream>>>(xh, Wh, b, cc, nvsq, tsq, out);
}